// Round 2
// baseline (24541.707 us; speedup 1.0000x reference)
//
#include <hip/hip_runtime.h>

// ---------------------------------------------------------------------------
// KokoroModel: emb -> biLSTM enc -> proj -> dur MLP -> length-regulate ->
//              MHA (teacher-forced) -> dec LSTM -> mel proj
// B=8, T_TEXT=256, T_MEL=1024, H=512, MEL=80, NH=8, HD=64
// All float tensors fp32 (per reference dtypes). Internal compute fp32.
// ---------------------------------------------------------------------------

typedef unsigned short u16;
typedef unsigned int u32;

#define BB 8
#define TT 256
#define TM 1024
#define HH 512
#define MELC 80
#define G4 2048   // 4*H

__device__ __forceinline__ float sigmoidf_(float x) { return 1.f / (1.f + __expf(-x)); }

// ------------------------- workspace layout (floats) -----------------------
// STATE: 3 scans x [hA(4096), hB(4096), c(4096)]
#define O_STATE   0u
#define O_LOGDUR  36864u
#define O_KIDX    38912u            /* 8192 ints */
#define O_ENC     47104u            /* 2048x512 */
#define O_R1      1095680u          /* 4M: hf|hb|cat  -> exp -> ctx */
#define O_ATT     5289984u          /* 4M attended */
#define O_QIN     9484288u          /* 4M q_in */
#define O_BIG2    13678592u         /* 8M: q|k -> dec_in -> h_dec|mel_f */
#define O_BIG1    22067200u         /* 16.8M: xg_f|xg_b|x -> h1|h2|v|mel_in -> xg_dec */
// sub-offsets
#define O_HF      (O_R1)
#define O_HB      (O_R1 + 1048576u)
#define O_CAT     (O_R1 + 2097152u)
#define O_EXP     (O_R1)
#define O_CTX     (O_R1)
#define O_Q       (O_BIG2)
#define O_K       (O_BIG2 + 4194304u)
#define O_DECIN   (O_BIG2)
#define O_HDEC    (O_BIG2)
#define O_MELF    (O_BIG2 + 4194304u)
#define O_XGF     (O_BIG1)
#define O_XGB     (O_BIG1 + 4194304u)
#define O_X       (O_BIG1 + 8388608u)
#define O_H1      (O_BIG1 + 8388608u)
#define O_H2      (O_BIG1 + 9437184u)
#define O_V       (O_BIG1 + 10485760u)
#define O_MELIN   (O_BIG1 + 14680064u)
#define O_XGD     (O_BIG1)

// ---------------------------------------------------------------------------
__global__ __launch_bounds__(256) void zero_kernel(float* p, int n) {
    int i = blockIdx.x * 256 + threadIdx.x;
    if (i < n) p[i] = 0.f;
}

__global__ __launch_bounds__(256) void embed_kernel(const int* idx, const float* emb, float* x) {
    int i = blockIdx.x * 256 + threadIdx.x;      // over 2048*512
    int tok = i >> 9, h = i & 511;
    x[i] = emb[(size_t)idx[tok] * HH + h];
}

// C[M,N] = act(A[M,K] @ W[N,K]^T + bias[N]);  all fp32.
// 128x128 tile, BK=16, 256 threads, 8x8 micro-tile.
template <int ACT>
__global__ __launch_bounds__(256) void gemm_bt(const float* __restrict__ A,
                                               const float* __restrict__ W,
                                               const float* __restrict__ bias,
                                               float* __restrict__ C,
                                               int M, int N, int K) {
    __shared__ float As[16][129];
    __shared__ float Ws[16][129];
    const int bm = blockIdx.y * 128, bn = blockIdx.x * 128;
    const int tid = threadIdx.x;
    const int tx = tid & 15, ty = tid >> 4;
    float acc[8][8];
#pragma unroll
    for (int i = 0; i < 8; i++)
#pragma unroll
        for (int j = 0; j < 8; j++) acc[i][j] = 0.f;

    for (int k0 = 0; k0 < K; k0 += 16) {
#pragma unroll
        for (int i = 0; i < 8; i++) {
            int idx = tid + i * 256;             // 0..2047
            int m = idx >> 4, kk = idx & 15;
            float va = 0.f, vw = 0.f;
            if (bm + m < M && k0 + kk < K) va = A[(size_t)(bm + m) * K + k0 + kk];
            if (bn + m < N && k0 + kk < K) vw = W[(size_t)(bn + m) * K + k0 + kk];
            As[kk][m] = va;
            Ws[kk][m] = vw;
        }
        __syncthreads();
#pragma unroll
        for (int kk = 0; kk < 16; kk++) {
            float a[8], b[8];
#pragma unroll
            for (int i = 0; i < 8; i++) a[i] = As[kk][ty + 16 * i];
#pragma unroll
            for (int j = 0; j < 8; j++) b[j] = Ws[kk][tx + 16 * j];
#pragma unroll
            for (int i = 0; i < 8; i++)
#pragma unroll
                for (int j = 0; j < 8; j++) acc[i][j] += a[i] * b[j];
        }
        __syncthreads();
    }
#pragma unroll
    for (int i = 0; i < 8; i++) {
#pragma unroll
        for (int j = 0; j < 8; j++) {
            int m = bm + ty + 16 * i, n = bn + tx + 16 * j;
            if (m < M && n < N) {
                float v = acc[i][j] + (bias ? bias[n] : 0.f);
                if (ACT == 1) v = fmaxf(v, 0.f);
                C[(size_t)m * N + n] = v;
            }
        }
    }
}

// One LSTM timestep, two independent scans via blockIdx.y (fwd/bwd or single).
// grid.x = 64 blocks: b = blk>>3, j-chunk of 64; 256 thr = 64 j x 4 gates.
// state st: [hA(4096), hB(4096), c(4096)]; ping-pong on t parity.
__global__ __launch_bounds__(256) void lstm_step(
    const float* __restrict__ xg0, const float* __restrict__ xg1,
    const float* __restrict__ whh0, const float* __restrict__ whh1,
    const float* __restrict__ bhh0, const float* __restrict__ bhh1,
    float* st0, float* st1, float* hout0, float* hout1, int t, int seqT) {
    const int dir = blockIdx.y;
    const float* xg = dir ? xg1 : xg0;
    const float* whh = dir ? whh1 : whh0;
    const float* bhh = dir ? bhh1 : bhh0;
    float* st = dir ? st1 : st0;
    float* hout = dir ? hout1 : hout0;
    const int te = dir ? (seqT - 1 - t) : t;

    float* hr = st + ((t & 1) ? 4096 : 0);
    float* hw = st + ((t & 1) ? 0 : 4096);
    float* c = st + 8192;

    const int b = blockIdx.x >> 3;
    const int j0 = (blockIdx.x & 7) << 6;
    const int jl = threadIdx.x & 63;
    const int gate = threadIdx.x >> 6;
    const int j = j0 + jl;
    const int row = gate * HH + j;

    __shared__ float hs[512];
    __shared__ float sg[4][64];
    hs[threadIdx.x] = hr[b * HH + threadIdx.x];
    hs[threadIdx.x + 256] = hr[b * HH + 256 + threadIdx.x];
    __syncthreads();

    float acc = xg[(size_t)(b * seqT + te) * G4 + row] + bhh[row];
    const float4* wr = (const float4*)(whh + (size_t)row * HH);  // 128 x float4
#pragma unroll 8
    for (int kk = 0; kk < 128; kk++) {
        float4 w = wr[kk];
        const float* hp = &hs[kk * 4];
        acc += hp[0] * w.x + hp[1] * w.y + hp[2] * w.z + hp[3] * w.w;
    }
    sg[gate][jl] = acc;
    __syncthreads();
    if (gate == 0) {
        float i_ = sigmoidf_(sg[0][jl]);
        float f_ = sigmoidf_(sg[1][jl]);
        float g_ = tanhf(sg[2][jl]);
        float o_ = sigmoidf_(sg[3][jl]);
        float cv = c[b * HH + j];
        float cn = f_ * cv + i_ * g_;
        float hn = o_ * tanhf(cn);
        c[b * HH + j] = cn;
        hw[b * HH + j] = hn;
        hout[(size_t)(b * seqT + te) * HH + j] = hn;
    }
}

__global__ __launch_bounds__(256) void cat_kernel(const float* hf, const float* hb, float* cat) {
    int i = blockIdx.x * 256 + threadIdx.x;      // over 2048*1024
    int row = i >> 10, h = i & 1023;
    cat[i] = (h < HH) ? hf[(size_t)row * HH + h] : hb[(size_t)row * HH + h - HH];
}

__global__ __launch_bounds__(256) void dur3_kernel(const float* __restrict__ h2,
                                                   const float* __restrict__ w,
                                                   const float* __restrict__ b, float* out) {
    int row = blockIdx.x * 256 + threadIdx.x;    // 2048
    float acc = b[0];
    const float* hp = h2 + (size_t)row * 256;
    for (int k = 0; k < 256; k++) acc += hp[k] * w[k];
    out[row] = acc;
}

// durations -> cumsum -> searchsorted index per mel position (-1 = pad)
__global__ __launch_bounds__(256) void length_reg_kernel(const float* __restrict__ dur, int* kidx) {
    int b = blockIdx.x;
    int t = threadIdx.x;
    __shared__ int cum[256];
    cum[t] = (int)rintf(dur[b * TT + t]);
    __syncthreads();
    for (int off = 1; off < 256; off <<= 1) {
        int val = (t >= off) ? cum[t - off] : 0;
        __syncthreads();
        cum[t] += val;
        __syncthreads();
    }
    int total = cum[255];
    for (int pos = t; pos < TM; pos += 256) {
        int lo = 0, hi = 256;
        while (lo < hi) {
            int mid = (lo + hi) >> 1;
            if (cum[mid] <= pos) lo = mid + 1; else hi = mid;
        }
        int idx = (pos < total) ? ((lo < 255) ? lo : 255) : -1;
        kidx[b * TM + pos] = idx;
    }
}

__global__ __launch_bounds__(256) void expand_kernel(const float* __restrict__ enc,
                                                     const int* __restrict__ kidx, float* exp_) {
    int i = blockIdx.x * 256 + threadIdx.x;      // over 8192*512
    int row = i >> 9, h = i & 511;               // row = b*1024 + pos
    int b = row >> 10;
    int id = kidx[row];
    exp_[i] = (id >= 0) ? enc[(size_t)(b * TT + id) * HH + h] : 0.f;
}

__global__ __launch_bounds__(256) void melin_kernel(const float* __restrict__ mel, float* mel_in) {
    int i = blockIdx.x * 256 + threadIdx.x;      // over 8192*80
    if (i >= BB * TM * MELC) return;
    int row = i / MELC, cc = i - row * MELC;
    int b = row >> 10, tpos = row & 1023;
    mel_in[i] = (tpos == 0) ? 0.f : mel[(size_t)(b * TM + tpos - 1) * MELC + cc];
}

// Flash-style MHA: one q-row per thread; K/V tiles (32x64) in LDS.
// grid = (4, 64): blockIdx.y = b*8+h, blockIdx.x = q-chunk of 256.
__global__ __launch_bounds__(256) void attn_kernel(const float* __restrict__ q,
                                                   const float* __restrict__ k,
                                                   const float* __restrict__ v,
                                                   const int* __restrict__ kidx,
                                                   float* __restrict__ ctx) {
    const int bh = blockIdx.y;
    const int b = bh >> 3, h = bh & 7;
    const int qrow = blockIdx.x * 256 + threadIdx.x;
    __shared__ float Ks[32][64];
    __shared__ float Vs[32][64];
    __shared__ float spad[32];

    float qr[64], acc[64];
    const float* qp = q + (size_t)(b * TM + qrow) * HH + h * 64;
#pragma unroll
    for (int d = 0; d < 64; d++) qr[d] = qp[d] * 0.125f;
#pragma unroll
    for (int d = 0; d < 64; d++) acc[d] = 0.f;
    float m = -1e30f, l = 0.f;

    for (int k0 = 0; k0 < TM; k0 += 32) {
        __syncthreads();
#pragma unroll
        for (int i = 0; i < 8; i++) {
            int idx = threadIdx.x + i * 256;     // 0..2047
            int r = idx >> 6, d = idx & 63;
            size_t off = (size_t)(b * TM + k0 + r) * HH + h * 64 + d;
            Ks[r][d] = k[off];
            Vs[r][d] = v[off];
        }
        if (threadIdx.x < 32)
            spad[threadIdx.x] = (kidx[b * TM + k0 + threadIdx.x] < 0) ? 1.f : 0.f;
        __syncthreads();
        for (int r = 0; r < 32; r++) {
            float s = 0.f;
#pragma unroll
            for (int d = 0; d < 64; d++) s += qr[d] * Ks[r][d];
            if (spad[r] != 0.f) s = -1e9f;
            float mn = fmaxf(m, s);
            float corr = __expf(m - mn);
            float p = __expf(s - mn);
            l = l * corr + p;
#pragma unroll
            for (int d = 0; d < 64; d++) acc[d] = acc[d] * corr + p * Vs[r][d];
            m = mn;
        }
    }
    float inv = 1.f / l;
    float* op = ctx + (size_t)(b * TM + qrow) * HH + h * 64;
#pragma unroll
    for (int d = 0; d < 64; d++) op[d] = acc[d] * inv;
}

__global__ __launch_bounds__(256) void decin_kernel(const float* q_in, const float* att, float* dec_in) {
    int i = blockIdx.x * 256 + threadIdx.x;      // over 8192*1024
    int row = i >> 10, h = i & 1023;
    dec_in[i] = (h < HH) ? q_in[(size_t)row * HH + h] : att[(size_t)row * HH + h - HH];
}

__global__ __launch_bounds__(256) void finalize_kernel(const float* melf, const float* logdur, float* out) {
    int i = blockIdx.x * 256 + threadIdx.x;
    if (i < BB * TM * MELC) out[i] = melf[i];
    else if (i < BB * TM * MELC + BB * TT) out[i] = logdur[i - BB * TM * MELC];
}

// ---------------------------------------------------------------------------
extern "C" void kernel_launch(void* const* d_in, const int* in_sizes, int n_in,
                              void* d_out, int out_size, void* d_ws, size_t ws_size,
                              hipStream_t stream) {
    const int*   ph      = (const int*)d_in[0];
    const float* mel     = (const float*)d_in[1];
    const float* durs    = (const float*)d_in[2];
    const float* emb     = (const float*)d_in[3];
    const float* w_ih_f  = (const float*)d_in[4];
    const float* w_hh_f  = (const float*)d_in[5];
    const float* b_ih_f  = (const float*)d_in[6];
    const float* b_hh_f  = (const float*)d_in[7];
    const float* w_ih_b  = (const float*)d_in[8];
    const float* w_hh_b  = (const float*)d_in[9];
    const float* b_ih_b  = (const float*)d_in[10];
    const float* b_hh_b  = (const float*)d_in[11];
    const float* proj_w  = (const float*)d_in[12];
    const float* proj_b  = (const float*)d_in[13];
    const float* dur_w1  = (const float*)d_in[14];
    const float* dur_b1  = (const float*)d_in[15];
    const float* dur_w2  = (const float*)d_in[16];
    const float* dur_b2  = (const float*)d_in[17];
    const float* dur_w3  = (const float*)d_in[18];
    const float* dur_b3  = (const float*)d_in[19];
    const float* melin_w = (const float*)d_in[20];
    const float* melin_b = (const float*)d_in[21];
    const float* attin_w = (const float*)d_in[22];
    const float* attin_b = (const float*)d_in[23];
    const float* atout_w = (const float*)d_in[24];
    const float* atout_b = (const float*)d_in[25];
    const float* dec_wih = (const float*)d_in[26];
    const float* dec_whh = (const float*)d_in[27];
    const float* dec_bih = (const float*)d_in[28];
    const float* dec_bhh = (const float*)d_in[29];
    const float* melo_w  = (const float*)d_in[30];
    const float* melo_b  = (const float*)d_in[31];

    float* ws = (float*)d_ws;
    float* st_ef = ws + O_STATE;
    float* st_eb = ws + O_STATE + 12288;
    float* st_d  = ws + O_STATE + 24576;
    int*   kidx  = (int*)(ws + O_KIDX);

    dim3 b256(256);
    auto gemm = [&](const float* A, const float* W, const float* bias, float* C,
                    int M, int N, int K, int act) {
        dim3 g((N + 127) / 128, (M + 127) / 128);
        if (act) gemm_bt<1><<<g, b256, 0, stream>>>(A, W, bias, C, M, N, K);
        else     gemm_bt<0><<<g, b256, 0, stream>>>(A, W, bias, C, M, N, K);
    };

    // 0) zero LSTM states (ws is poisoned each call)
    zero_kernel<<<(36864 + 255) / 256, b256, 0, stream>>>(ws + O_STATE, 36864);

    // 1) embedding -> x [2048,512]
    embed_kernel<<<(2048 * 512) / 256, b256, 0, stream>>>(ph, emb, ws + O_X);

    // 2) encoder xg = x@W_ih^T + b_ih  [2048,2048] per dir
    gemm(ws + O_X, w_ih_f, b_ih_f, ws + O_XGF, 2048, G4, HH, 0);
    gemm(ws + O_X, w_ih_b, b_ih_b, ws + O_XGB, 2048, G4, HH, 0);

    // 3) encoder scans (fwd + bwd in one launch via grid.y)
    for (int t = 0; t < TT; t++)
        lstm_step<<<dim3(64, 2), b256, 0, stream>>>(ws + O_XGF, ws + O_XGB,
                                                    w_hh_f, w_hh_b, b_hh_f, b_hh_b,
                                                    st_ef, st_eb, ws + O_HF, ws + O_HB, t, TT);

    // 4) proj([hf,hb]) -> enc [2048,512]
    cat_kernel<<<(2048 * 1024) / 256, b256, 0, stream>>>(ws + O_HF, ws + O_HB, ws + O_CAT);
    gemm(ws + O_CAT, proj_w, proj_b, ws + O_ENC, 2048, HH, 2 * HH, 0);

    // 5) duration predictor
    gemm(ws + O_ENC, dur_w1, dur_b1, ws + O_H1, 2048, HH, HH, 1);
    gemm(ws + O_H1, dur_w2, dur_b2, ws + O_H2, 2048, 256, HH, 1);
    dur3_kernel<<<8, b256, 0, stream>>>(ws + O_H2, dur_w3, dur_b3, ws + O_LOGDUR);

    // 6) length regulation
    length_reg_kernel<<<8, b256, 0, stream>>>(durs, kidx);
    expand_kernel<<<(8192 * 512) / 256, b256, 0, stream>>>(ws + O_ENC, kidx, ws + O_EXP);

    // 7) q_in = Linear(mel shifted) [8192,512]
    melin_kernel<<<(8192 * MELC + 255) / 256, b256, 0, stream>>>(mel, ws + O_MELIN);
    gemm(ws + O_MELIN, melin_w, melin_b, ws + O_QIN, 8192, HH, MELC, 0);

    // 8) q,k,v projections (attn_in_w rows: [wq;wk;wv])
    gemm(ws + O_QIN, attin_w,              attin_b,        ws + O_Q, 8192, HH, HH, 0);
    gemm(ws + O_EXP, attin_w + 512 * 512,  attin_b + 512,  ws + O_K, 8192, HH, HH, 0);
    gemm(ws + O_EXP, attin_w + 1024 * 512, attin_b + 1024, ws + O_V, 8192, HH, HH, 0);

    // 9) attention -> ctx; out projection -> attended
    attn_kernel<<<dim3(4, 64), b256, 0, stream>>>(ws + O_Q, ws + O_K, ws + O_V, kidx, ws + O_CTX);
    gemm(ws + O_CTX, atout_w, atout_b, ws + O_ATT, 8192, HH, HH, 0);

    // 10) decoder: dec_in = [q_in, attended]; xg = dec_in@W_ih^T + b_ih
    decin_kernel<<<(8192 * 1024) / 256, b256, 0, stream>>>(ws + O_QIN, ws + O_ATT, ws + O_DECIN);
    gemm(ws + O_DECIN, dec_wih, dec_bih, ws + O_XGD, 8192, G4, 2 * HH, 0);

    // 11) decoder scan (single direction)
    for (int t = 0; t < TM; t++)
        lstm_step<<<dim3(64, 1), b256, 0, stream>>>(ws + O_XGD, ws + O_XGD,
                                                    dec_whh, dec_whh, dec_bhh, dec_bhh,
                                                    st_d, st_d, ws + O_HDEC, ws + O_HDEC, t, TM);

    // 12) mel projection + pack outputs
    gemm(ws + O_HDEC, melo_w, melo_b, ws + O_MELF, 8192, MELC, HH, 0);
    finalize_kernel<<<(BB * TM * MELC + BB * TT + 255) / 256, b256, 0, stream>>>(
        ws + O_MELF, ws + O_LOGDUR, (float*)d_out);
}